// Round 6
// baseline (457.515 us; speedup 1.0000x reference)
//
#include <hip/hip_runtime.h>
#include <hip/hip_bf16.h>
#include <math.h>

// GCN 2-layer forward. Round-6 (= round-5 fixed): two-level edge sort
// (dst-bucket, then src-group) so the aggregation gather window is an ~800KB
// slice of h1b -> stays L2-resident. Agg grid is group-major so co-resident
// blocks share the same slice. Nontemporal loads/stores keep edge/partial
// streams from thrashing L2. Native clang vector types for nontemporal builtins.

#define F_IN 128
#define H1 16
#define C_OUT 2
#define NPB 128        // nodes per dst bucket (dst >> 7)
#define LOG_NPB 7
#define CH 4096        // edges per partition chunk
#define K_MAX 1024     // max buckets / chunks for the scans

typedef float fx4 __attribute__((ext_vector_type(4)));
typedef float fx2 __attribute__((ext_vector_type(2)));

__device__ __forceinline__ float bflo(unsigned u) { return __uint_as_float(u << 16); }
__device__ __forceinline__ float bfhi(unsigned u) { return __uint_as_float(u & 0xFFFF0000u); }

// ---- pass A: per-chunk histogram of dst buckets; cnt layout [K][nblk] ----
__global__ __launch_bounds__(256) void k_part_count(
    const int* __restrict__ dst0, int* __restrict__ cnt, int E, int K, int nblk) {
    __shared__ int sc[K_MAX];
    for (int i = threadIdx.x; i < K; i += 256) sc[i] = 0;
    __syncthreads();
    int e0 = blockIdx.x * CH, e1 = min(e0 + CH, E);
    for (int e = e0 + threadIdx.x; e < e1; e += 256)
        atomicAdd(&sc[((unsigned)dst0[e]) >> LOG_NPB], 1);
    __syncthreads();
    for (int b = threadIdx.x; b < K; b += 256)
        cnt[(size_t)b * nblk + blockIdx.x] = sc[b];
}

// ---- pass B1: per-bucket exclusive scan over chunks (block per bucket) ----
__global__ __launch_bounds__(1024) void k_colscan(
    int* __restrict__ cnt, int* __restrict__ tot, int nblk) {
    __shared__ int s[K_MAX];
    int t = threadIdx.x;
    int* row = cnt + (size_t)blockIdx.x * nblk;
    int own = (t < nblk) ? row[t] : 0;
    s[t] = own;
    __syncthreads();
    for (int off = 1; off < K_MAX; off <<= 1) {
        int v = (t >= off) ? s[t - off] : 0;
        __syncthreads();
        s[t] += v;
        __syncthreads();
    }
    if (t < nblk) row[t] = s[t] - own;              // exclusive
    if (t == 0) tot[blockIdx.x] = s[K_MAX - 1];
}

// ---- pass B2: exclusive scan over bucket totals -> base_e ----
__global__ __launch_bounds__(1024) void k_basescan(
    const int* __restrict__ tot, int* __restrict__ base_e, int K) {
    __shared__ int s[K_MAX];
    int t = threadIdx.x;
    s[t] = (t < K) ? tot[t] : 0;
    __syncthreads();
    for (int off = 1; off < K_MAX; off <<= 1) {
        int v = (t >= off) ? s[t - off] : 0;
        __syncthreads();
        s[t] += v;
        __syncthreads();
    }
    if (t == 0) base_e[0] = 0;
    if (t < K) base_e[t + 1] = s[t];   // base_e[K] == E
}

// ---- pass C: scatter packed edges (src | dst_local<<24) into bucket order ----
__global__ __launch_bounds__(256) void k_scatter(
    const int* __restrict__ src0, const int* __restrict__ dst0,
    const int* __restrict__ cnt, const int* __restrict__ base_e,
    int* __restrict__ packed, int E, int K, int nblk) {
    __shared__ int cur[K_MAX];
    int blk = blockIdx.x;
    for (int b = threadIdx.x; b < K; b += 256)
        cur[b] = base_e[b] + cnt[(size_t)b * nblk + blk];
    __syncthreads();
    int e0 = blk * CH, e1 = min(e0 + CH, E);
    for (int e = e0 + threadIdx.x; e < e1; e += 256) {
        unsigned d = (unsigned)dst0[e];
        int b = d >> LOG_NPB;
        int pos = atomicAdd(&cur[b], 1);
        packed[pos] = src0[e] | ((d & (NPB - 1)) << 24);
    }
}

// ---- pass D: within each bucket, counting-sort edges by src-group ----
__global__ __launch_bounds__(256) void k_gsort(
    const int* __restrict__ packed, const int* __restrict__ base_e,
    int* __restrict__ packed2, int* __restrict__ seg_e,
    int K, int G, float ginv, int E) {
    __shared__ int cnt[8];
    __shared__ int cur[8];
    int b = blockIdx.x, t = threadIdx.x;
    if (t < G) cnt[t] = 0;
    __syncthreads();
    int e0 = base_e[b], e1 = base_e[b + 1];
    for (int e = e0 + t; e < e1; e += 256) {
        int p = __builtin_nontemporal_load(&packed[e]);
        int g = min(G - 1, (int)((float)(p & 0xFFFFFF) * ginv));
        atomicAdd(&cnt[g], 1);
    }
    __syncthreads();
    if (t == 0) {
        int run = e0;
        for (int g = 0; g < G; ++g) { cur[g] = run; seg_e[b * G + g] = run; run += cnt[g]; }
    }
    __syncthreads();
    for (int e = e0 + t; e < e1; e += 256) {
        int p = __builtin_nontemporal_load(&packed[e]);
        int g = min(G - 1, (int)((float)(p & 0xFFFFFF) * ginv));
        int pos = atomicAdd(&cur[g], 1);
        packed2[pos] = p;
    }
    if (b == 0 && t == 0) seg_e[K * G] = E;
}

// ---- degree -> dinv (block per bucket) ----
__global__ __launch_bounds__(1024) void k_deg(
    const int* __restrict__ packed, const int* __restrict__ base_e,
    float* __restrict__ dinv, int N) {
    __shared__ int cnt[NPB];
    int b = blockIdx.x, t = threadIdx.x;
    if (t < NPB) cnt[t] = 0;
    __syncthreads();
    int e0 = base_e[b], e1 = base_e[b + 1];
    for (int e = e0 + t; e < e1; e += 1024)
        atomicAdd(&cnt[(((unsigned)packed[e]) >> 24) & (NPB - 1)], 1);
    __syncthreads();
    if (t < NPB) {
        int node = b * NPB + t;
        if (node < N) dinv[node] = rsqrtf((float)(cnt[t] + 1));  // +1 self-loop
    }
}

// ---- layer 1 GEMM: h1b = bf16((x@W1)*dinv) ----
__global__ __launch_bounds__(256) void k_gemm1(
    const float* __restrict__ x, const float* __restrict__ W1,
    const float* __restrict__ dinv, __hip_bfloat16* __restrict__ h1b, int N) {
    __shared__ float w[F_IN * H1];    // 8 KB
    __shared__ float xt[16 * F_IN];   // 8 KB
    int tid = threadIdx.x;
    int node0 = blockIdx.x * 16;

    const float4* W14 = (const float4*)W1;
    float4* w4 = (float4*)w;
    for (int i = tid; i < F_IN * H1 / 4; i += 256) w4[i] = W14[i];

    const float4* x4 = (const float4*)x;
    float4* xt4 = (float4*)xt;
    for (int i = tid; i < 16 * F_IN / 4; i += 256) {
        int r = i >> 5;
        int node = node0 + r;
        xt4[i] = (node < N) ? x4[(size_t)node * 32 + (i & 31)]
                            : make_float4(0.f, 0.f, 0.f, 0.f);
    }
    __syncthreads();

    int nsub = tid >> 4, f = tid & 15;
    int node = node0 + nsub;
    if (node < N) {
        const float* xr = xt + nsub * F_IN;
        float acc = 0.0f;
        #pragma unroll 16
        for (int k = 0; k < F_IN; ++k)
            acc = fmaf(xr[k], w[k * H1 + f], acc);
        h1b[(size_t)node * H1 + f] = __float2bfloat16(acc * dinv[node]);
    }
}

// ---- layer 1 aggregation: grid (g-major) over (src-group, dst-bucket) ----
// 2 threads/edge (16B halves of the 32B bf16 row), 8 edges in flight/thread.
#define U1 8
__global__ __launch_bounds__(256) void k_agg1(
    const int* __restrict__ packed2, const int* __restrict__ seg_e,
    const __hip_bfloat16* __restrict__ h1b, float* __restrict__ part1,
    int K, int G) {
    __shared__ float acc[NPB * 17];   // odd stride -> atomics spread across banks
    int bid = blockIdx.x;
    int g = bid / K, b = bid - g * K;
    int key = b * G + g;
    int t = threadIdx.x;
    for (int i = t; i < NPB * 17; i += 256) acc[i] = 0.f;
    __syncthreads();

    int es = seg_e[key], ee = seg_e[key + 1];

    int lg = t >> 1, q = t & 1;          // 128 edge lanes, q = feature half
    const uint4* h4 = (const uint4*)h1b;
    for (int e = es + lg; e < ee; e += 128 * U1) {
        uint4 v[U1]; int dd[U1]; bool ok[U1];
        #pragma unroll
        for (int u = 0; u < U1; ++u) {
            int eu = e + u * 128;
            ok[u] = eu < ee;
            unsigned p = ok[u] ? (unsigned)__builtin_nontemporal_load(&packed2[eu]) : 0u;
            dd[u] = (p >> 24) & (NPB - 1);
            v[u] = h4[(size_t)(p & 0xFFFFFF) * 2 + q];   // p=0 safe
        }
        #pragma unroll
        for (int u = 0; u < U1; ++u) {
            if (ok[u]) {
                float* ap = acc + dd[u] * 17 + q * 8;
                atomicAdd(ap + 0, bflo(v[u].x));
                atomicAdd(ap + 1, bfhi(v[u].x));
                atomicAdd(ap + 2, bflo(v[u].y));
                atomicAdd(ap + 3, bfhi(v[u].y));
                atomicAdd(ap + 4, bflo(v[u].z));
                atomicAdd(ap + 5, bfhi(v[u].z));
                atomicAdd(ap + 6, bflo(v[u].w));
                atomicAdd(ap + 7, bfhi(v[u].w));
            }
        }
    }
    __syncthreads();
    // write [NPB][16] partials (strip pad), nontemporal
    fx4* po = (fx4*)(part1 + (size_t)key * (NPB * H1));
    for (int i = t; i < NPB * H1 / 4; i += 256) {
        int r = i >> 2, c = (i & 3) * 4;
        const float* sp = acc + r * 17 + c;
        fx4 v = {sp[0], sp[1], sp[2], sp[3]};
        __builtin_nontemporal_store(v, &po[i]);
    }
}

// ---- merge1: (sum partials + self)*dinv, +b1, relu, @W2, pre-scale -> h2s ----
__global__ __launch_bounds__(256) void k_merge1(
    const float* __restrict__ part1, const __hip_bfloat16* __restrict__ h1b,
    const float* __restrict__ dinv, const float* __restrict__ b1,
    const float* __restrict__ W2, float* __restrict__ h2s, int N, int G) {
    int n = blockIdx.x * 256 + threadIdx.x;
    if (n >= N) return;
    int b = n >> LOG_NPB, d = n & (NPB - 1);
    float dv = dinv[n];
    float a[H1];
    const uint4* hh = (const uint4*)h1b;
    uint4 s0 = hh[(size_t)n * 2 + 0];
    uint4 s1 = hh[(size_t)n * 2 + 1];
    a[0] = bflo(s0.x); a[1] = bfhi(s0.x); a[2] = bflo(s0.y); a[3] = bfhi(s0.y);
    a[4] = bflo(s0.z); a[5] = bfhi(s0.z); a[6] = bflo(s0.w); a[7] = bfhi(s0.w);
    a[8] = bflo(s1.x); a[9] = bfhi(s1.x); a[10]= bflo(s1.y); a[11]= bfhi(s1.y);
    a[12]= bflo(s1.z); a[13]= bfhi(s1.z); a[14]= bflo(s1.w); a[15]= bfhi(s1.w);
    for (int s = 0; s < G; ++s) {
        const fx4* pp = (const fx4*)(part1 + ((size_t)(b * G + s) * NPB + d) * H1);
        #pragma unroll
        for (int qq = 0; qq < 4; ++qq) {
            fx4 v = __builtin_nontemporal_load(&pp[qq]);
            a[qq*4+0] += v.x; a[qq*4+1] += v.y;
            a[qq*4+2] += v.z; a[qq*4+3] += v.w;
        }
    }
    float c0 = 0.f, c1 = 0.f;
    #pragma unroll
    for (int f = 0; f < H1; ++f) {
        float v = fmaxf(fmaf(a[f], dv, b1[f]), 0.f);
        c0 = fmaf(v, W2[f * C_OUT + 0], c0);
        c1 = fmaf(v, W2[f * C_OUT + 1], c1);
    }
    ((float2*)h2s)[n] = make_float2(c0 * dv, c1 * dv);
}

// ---- layer 2 aggregation: same (group, bucket) structure ----
#define U2 4
__global__ __launch_bounds__(256) void k_agg2(
    const int* __restrict__ packed2, const int* __restrict__ seg_e,
    const float* __restrict__ h2s, float* __restrict__ part2, int K, int G) {
    __shared__ float acc[NPB * 3];
    int bid = blockIdx.x;
    int g = bid / K, b = bid - g * K;
    int key = b * G + g;
    int t = threadIdx.x;
    for (int i = t; i < NPB * 3; i += 256) acc[i] = 0.f;
    __syncthreads();

    int es = seg_e[key], ee = seg_e[key + 1];

    const float2* h2 = (const float2*)h2s;
    for (int e = es + t; e < ee; e += 256 * U2) {
        float2 v[U2]; int dd[U2]; bool ok[U2];
        #pragma unroll
        for (int u = 0; u < U2; ++u) {
            int eu = e + u * 256;
            ok[u] = eu < ee;
            unsigned p = ok[u] ? (unsigned)__builtin_nontemporal_load(&packed2[eu]) : 0u;
            dd[u] = (p >> 24) & (NPB - 1);
            v[u] = h2[p & 0xFFFFFF];
        }
        #pragma unroll
        for (int u = 0; u < U2; ++u) {
            if (ok[u]) {
                atomicAdd(&acc[dd[u] * 3 + 0], v[u].x);
                atomicAdd(&acc[dd[u] * 3 + 1], v[u].y);
            }
        }
    }
    __syncthreads();
    fx2* po = (fx2*)(part2 + (size_t)key * (NPB * 2));
    for (int i = t; i < NPB; i += 256) {
        fx2 v = {acc[i * 3 + 0], acc[i * 3 + 1]};
        __builtin_nontemporal_store(v, &po[i]);
    }
}

// ---- merge2: (sum partials + self)*dinv + b2, log_softmax -> out ----
__global__ __launch_bounds__(256) void k_merge2(
    const float* __restrict__ part2, const float* __restrict__ h2s,
    const float* __restrict__ dinv, const float* __restrict__ b2,
    float* __restrict__ out, int N, int G) {
    int n = blockIdx.x * 256 + threadIdx.x;
    if (n >= N) return;
    int b = n >> LOG_NPB, d = n & (NPB - 1);
    float dv = dinv[n];
    float2 h = ((const float2*)h2s)[n];
    float a0 = h.x, a1 = h.y;
    const fx2* p2 = (const fx2*)part2;
    for (int s = 0; s < G; ++s) {
        fx2 v = __builtin_nontemporal_load(&p2[(size_t)(b * G + s) * NPB + d]);
        a0 += v.x; a1 += v.y;
    }
    a0 = fmaf(a0, dv, b2[0]);
    a1 = fmaf(a1, dv, b2[1]);
    float m = fmaxf(a0, a1);
    float lse = m + logf(expf(a0 - m) + expf(a1 - m));
    ((float2*)out)[n] = make_float2(a0 - lse, a1 - lse);
}

extern "C" void kernel_launch(void* const* d_in, const int* in_sizes, int n_in,
                              void* d_out, int out_size, void* d_ws, size_t ws_size,
                              hipStream_t stream) {
    const float* x  = (const float*)d_in[0];
    const int* ei   = (const int*)d_in[1];
    const float* W1 = (const float*)d_in[2];
    const float* b1 = (const float*)d_in[3];
    const float* W2 = (const float*)d_in[4];
    const float* b2 = (const float*)d_in[5];
    float* out = (float*)d_out;

    const int N = in_sizes[0] / F_IN;     // 100000
    const int E = in_sizes[1] / 2;        // 3200000
    const int* src0 = ei;
    const int* dst0 = ei + E;

    const int K = (N + NPB - 1) >> LOG_NPB;      // 782
    const int nblk = (E + CH - 1) / CH;          // 782

    // adaptive src-group count based on ws capacity
    size_t fixed_f = (size_t)N * (1 + H1 / 2 + C_OUT) + 2 * (size_t)E
                   + (size_t)K * nblk + K + (K + 1) + 64;
    size_t perG_f = (size_t)K * (NPB * H1 + NPB * C_OUT + 1);
    size_t avail_f = ws_size / 4;
    int G = 4;
    while (G > 1 && fixed_f + (size_t)G * perG_f + 1 > avail_f) G >>= 1;
    float ginv = (float)G / (float)N;

    // workspace layout (float units), 16B-aligned chunks
    size_t off = 0;
    float* wsf = (float*)d_ws;
    auto take = [&](size_t nf) { float* p = wsf + off; off += (nf + 3) & ~(size_t)3; return p; };
    float* dinv    = take(N);
    __hip_bfloat16* h1b = (__hip_bfloat16*)take((size_t)N * H1 / 2);
    float* h2s     = take((size_t)N * C_OUT);
    int*   packed  = (int*)take(E);
    int*   packed2 = (int*)take(E);
    int*   cnt     = (int*)take((size_t)K * nblk);
    int*   tot     = (int*)take(K);
    int*   base_e  = (int*)take(K + 1);
    int*   seg_e   = (int*)take((size_t)K * G + 1);
    float* part1   = take((size_t)K * G * NPB * H1);
    float* part2   = take((size_t)K * G * NPB * C_OUT);

    int nbN = (N + 255) / 256;

    k_part_count<<<nblk, 256, 0, stream>>>(dst0, cnt, E, K, nblk);
    k_colscan<<<K, 1024, 0, stream>>>(cnt, tot, nblk);
    k_basescan<<<1, 1024, 0, stream>>>(tot, base_e, K);
    k_scatter<<<nblk, 256, 0, stream>>>(src0, dst0, cnt, base_e, packed, E, K, nblk);
    k_gsort<<<K, 256, 0, stream>>>(packed, base_e, packed2, seg_e, K, G, ginv, E);
    k_deg<<<K, 1024, 0, stream>>>(packed, base_e, dinv, N);
    k_gemm1<<<(N + 15) / 16, 256, 0, stream>>>(x, W1, dinv, h1b, N);
    k_agg1<<<K * G, 256, 0, stream>>>(packed2, seg_e, h1b, part1, K, G);
    k_merge1<<<nbN, 256, 0, stream>>>(part1, h1b, dinv, b1, W2, h2s, N, G);
    k_agg2<<<K * G, 256, 0, stream>>>(packed2, seg_e, h2s, part2, K, G);
    k_merge2<<<nbN, 256, 0, stream>>>(part2, h2s, dinv, b2, out, N, G);
}

// Round 7
// 171.224 us; speedup vs baseline: 2.6720x; 2.6720x over previous
//
#include <hip/hip_runtime.h>
#include <hip/hip_bf16.h>
#include <math.h>

// GCN 2-layer forward, round-7: FULL dst-sort (bucket sort + per-bucket counting
// sort by dst_local) -> CSR row ranges rp[N+1]. Aggregation is thread-per-
// (node, feature-half) with REGISTER accumulation: no atomics anywhere in the
// hot path (the r2-r6 wall was the LDS atomic RMW pipe, ~290us invariant).
// Layer-2 transform fused into agg1 epilogue; log_softmax fused into agg2.

#define F_IN 128
#define H1 16
#define C_OUT 2
#define NPB 128        // nodes per dst bucket (dst >> 7)
#define LOG_NPB 7
#define CH 4096        // edges per partition chunk
#define K_MAX 1024     // max buckets / chunks for the scans

__device__ __forceinline__ float bflo(unsigned u) { return __uint_as_float(u << 16); }
__device__ __forceinline__ float bfhi(unsigned u) { return __uint_as_float(u & 0xFFFF0000u); }

// ---- pass A: per-chunk histogram of dst buckets; cnt layout [K][nblk] ----
__global__ __launch_bounds__(256) void k_part_count(
    const int* __restrict__ dst0, int* __restrict__ cnt, int E, int K, int nblk) {
    __shared__ int sc[K_MAX];
    for (int i = threadIdx.x; i < K; i += 256) sc[i] = 0;
    __syncthreads();
    int e0 = blockIdx.x * CH, e1 = min(e0 + CH, E);
    for (int e = e0 + threadIdx.x; e < e1; e += 256)
        atomicAdd(&sc[((unsigned)dst0[e]) >> LOG_NPB], 1);
    __syncthreads();
    for (int b = threadIdx.x; b < K; b += 256)
        cnt[(size_t)b * nblk + blockIdx.x] = sc[b];
}

// ---- pass B1: per-bucket exclusive scan over chunks (block per bucket) ----
__global__ __launch_bounds__(1024) void k_colscan(
    int* __restrict__ cnt, int* __restrict__ tot, int nblk) {
    __shared__ int s[K_MAX];
    int t = threadIdx.x;
    int* row = cnt + (size_t)blockIdx.x * nblk;
    int own = (t < nblk) ? row[t] : 0;
    s[t] = own;
    __syncthreads();
    for (int off = 1; off < K_MAX; off <<= 1) {
        int v = (t >= off) ? s[t - off] : 0;
        __syncthreads();
        s[t] += v;
        __syncthreads();
    }
    if (t < nblk) row[t] = s[t] - own;              // exclusive
    if (t == 0) tot[blockIdx.x] = s[K_MAX - 1];
}

// ---- pass B2: exclusive scan over bucket totals -> base_e ----
__global__ __launch_bounds__(1024) void k_basescan(
    const int* __restrict__ tot, int* __restrict__ base_e, int K) {
    __shared__ int s[K_MAX];
    int t = threadIdx.x;
    s[t] = (t < K) ? tot[t] : 0;
    __syncthreads();
    for (int off = 1; off < K_MAX; off <<= 1) {
        int v = (t >= off) ? s[t - off] : 0;
        __syncthreads();
        s[t] += v;
        __syncthreads();
    }
    if (t == 0) base_e[0] = 0;
    if (t < K) base_e[t + 1] = s[t];   // base_e[K] == E
}

// ---- pass C: scatter packed edges (src | dst_local<<24) into bucket order ----
__global__ __launch_bounds__(256) void k_scatter(
    const int* __restrict__ src0, const int* __restrict__ dst0,
    const int* __restrict__ cnt, const int* __restrict__ base_e,
    int* __restrict__ packed, int E, int K, int nblk) {
    __shared__ int cur[K_MAX];
    int blk = blockIdx.x;
    for (int b = threadIdx.x; b < K; b += 256)
        cur[b] = base_e[b] + cnt[(size_t)b * nblk + blk];
    __syncthreads();
    int e0 = blk * CH, e1 = min(e0 + CH, E);
    for (int e = e0 + threadIdx.x; e < e1; e += 256) {
        unsigned d = (unsigned)dst0[e];
        int b = d >> LOG_NPB;
        int pos = atomicAdd(&cur[b], 1);
        packed[pos] = src0[e] | ((d & (NPB - 1)) << 24);
    }
}

// ---- pass D: per bucket: count dst_local -> scan -> rp/dinv -> sort by dst ----
__global__ __launch_bounds__(256) void k_bucket(
    const int* __restrict__ packed, const int* __restrict__ base_e,
    int* __restrict__ packed2, int* __restrict__ rp,
    float* __restrict__ dinv, int N, int K, int E) {
    __shared__ int cnt[NPB];
    __shared__ int sc[NPB];
    __shared__ int cur[NPB];
    int b = blockIdx.x, t = threadIdx.x;
    if (t < NPB) cnt[t] = 0;
    __syncthreads();
    int e0 = base_e[b], e1 = base_e[b + 1];
    for (int e = e0 + t; e < e1; e += 256)
        atomicAdd(&cnt[(((unsigned)packed[e]) >> 24) & (NPB - 1)], 1);
    __syncthreads();
    if (t < NPB) sc[t] = cnt[t];
    __syncthreads();
    #pragma unroll
    for (int off = 1; off < NPB; off <<= 1) {
        int v = (t < NPB && t >= off) ? sc[t - off] : 0;
        __syncthreads();
        if (t < NPB) sc[t] += v;
        __syncthreads();
    }
    if (t < NPB) {
        int excl = sc[t] - cnt[t];
        int node = b * NPB + t;
        if (node <= N) rp[node] = e0 + excl;
        if (node < N) dinv[node] = rsqrtf((float)(cnt[t] + 1));  // +1 self-loop
        cur[t] = e0 + excl;
    }
    if (b == 0 && t == 0) rp[N] = E;   // safety (same value as in-range write)
    __syncthreads();
    for (int e = e0 + t; e < e1; e += 256) {
        int p = packed[e];
        int d = (((unsigned)p) >> 24) & (NPB - 1);
        int pos = atomicAdd(&cur[d], 1);
        packed2[pos] = p;
    }
}

// ---- layer 1 GEMM: h1b = bf16((x@W1)*dinv) ----
__global__ __launch_bounds__(256) void k_gemm1(
    const float* __restrict__ x, const float* __restrict__ W1,
    const float* __restrict__ dinv, __hip_bfloat16* __restrict__ h1b, int N) {
    __shared__ float w[F_IN * H1];    // 8 KB
    __shared__ float xt[16 * F_IN];   // 8 KB
    int tid = threadIdx.x;
    int node0 = blockIdx.x * 16;

    const float4* W14 = (const float4*)W1;
    float4* w4 = (float4*)w;
    for (int i = tid; i < F_IN * H1 / 4; i += 256) w4[i] = W14[i];

    const float4* x4 = (const float4*)x;
    float4* xt4 = (float4*)xt;
    for (int i = tid; i < 16 * F_IN / 4; i += 256) {
        int r = i >> 5;
        int node = node0 + r;
        xt4[i] = (node < N) ? x4[(size_t)node * 32 + (i & 31)]
                            : make_float4(0.f, 0.f, 0.f, 0.f);
    }
    __syncthreads();

    int nsub = tid >> 4, f = tid & 15;
    int node = node0 + nsub;
    if (node < N) {
        const float* xr = xt + nsub * F_IN;
        float acc = 0.0f;
        #pragma unroll 16
        for (int k = 0; k < F_IN; ++k)
            acc = fmaf(xr[k], w[k * H1 + f], acc);
        h1b[(size_t)node * H1 + f] = __float2bfloat16(acc * dinv[node]);
    }
}

// ---- layer 1 aggregate + layer 2 transform, thread per (node, feature-half) ----
// Register accumulation over the node's contiguous (dst-sorted) edge run.
__global__ __launch_bounds__(256) void k_agg1(
    const int* __restrict__ packed2, const int* __restrict__ rp,
    const __hip_bfloat16* __restrict__ h1b, const float* __restrict__ dinv,
    const float* __restrict__ b1, const float* __restrict__ W2,
    float* __restrict__ h2s, int N) {
    int tid = blockIdx.x * 256 + threadIdx.x;
    int n = tid >> 1, q = tid & 1;
    if (n >= N) return;
    const uint4* h4 = (const uint4*)h1b;
    float a[8];
    {   // self-loop init: own pre-scaled row half
        uint4 s = h4[(size_t)n * 2 + q];
        a[0] = bflo(s.x); a[1] = bfhi(s.x); a[2] = bflo(s.y); a[3] = bfhi(s.y);
        a[4] = bflo(s.z); a[5] = bfhi(s.z); a[6] = bflo(s.w); a[7] = bfhi(s.w);
    }
    int e = rp[n], e1 = rp[n + 1];
    for (; e + 4 <= e1; e += 4) {
        int p0 = packed2[e + 0] & 0xFFFFFF;
        int p1 = packed2[e + 1] & 0xFFFFFF;
        int p2 = packed2[e + 2] & 0xFFFFFF;
        int p3 = packed2[e + 3] & 0xFFFFFF;
        uint4 v0 = h4[(size_t)p0 * 2 + q];
        uint4 v1 = h4[(size_t)p1 * 2 + q];
        uint4 v2 = h4[(size_t)p2 * 2 + q];
        uint4 v3 = h4[(size_t)p3 * 2 + q];
        a[0] += bflo(v0.x); a[1] += bfhi(v0.x); a[2] += bflo(v0.y); a[3] += bfhi(v0.y);
        a[4] += bflo(v0.z); a[5] += bfhi(v0.z); a[6] += bflo(v0.w); a[7] += bfhi(v0.w);
        a[0] += bflo(v1.x); a[1] += bfhi(v1.x); a[2] += bflo(v1.y); a[3] += bfhi(v1.y);
        a[4] += bflo(v1.z); a[5] += bfhi(v1.z); a[6] += bflo(v1.w); a[7] += bfhi(v1.w);
        a[0] += bflo(v2.x); a[1] += bfhi(v2.x); a[2] += bflo(v2.y); a[3] += bfhi(v2.y);
        a[4] += bflo(v2.z); a[5] += bfhi(v2.z); a[6] += bflo(v2.w); a[7] += bfhi(v2.w);
        a[0] += bflo(v3.x); a[1] += bfhi(v3.x); a[2] += bflo(v3.y); a[3] += bfhi(v3.y);
        a[4] += bflo(v3.z); a[5] += bfhi(v3.z); a[6] += bflo(v3.w); a[7] += bfhi(v3.w);
    }
    for (; e < e1; ++e) {
        int p = packed2[e] & 0xFFFFFF;
        uint4 v = h4[(size_t)p * 2 + q];
        a[0] += bflo(v.x); a[1] += bfhi(v.x); a[2] += bflo(v.y); a[3] += bfhi(v.y);
        a[4] += bflo(v.z); a[5] += bfhi(v.z); a[6] += bflo(v.w); a[7] += bfhi(v.w);
    }
    float dv = dinv[n];
    float c0 = 0.f, c1 = 0.f;
    #pragma unroll
    for (int j = 0; j < 8; ++j) {
        int f = q * 8 + j;
        float vv = fmaxf(fmaf(a[j], dv, b1[f]), 0.f);
        c0 = fmaf(vv, W2[f * C_OUT + 0], c0);
        c1 = fmaf(vv, W2[f * C_OUT + 1], c1);
    }
    c0 += __shfl_xor(c0, 1);
    c1 += __shfl_xor(c1, 1);
    if (q == 0)
        ((float2*)h2s)[n] = make_float2(c0 * dv, c1 * dv);
}

// ---- layer 2 aggregate + log_softmax, thread per node ----
__global__ __launch_bounds__(256) void k_agg2(
    const int* __restrict__ packed2, const int* __restrict__ rp,
    const float* __restrict__ h2s, const float* __restrict__ dinv,
    const float* __restrict__ b2, float* __restrict__ out, int N) {
    int n = blockIdx.x * 256 + threadIdx.x;
    if (n >= N) return;
    const float2* h2 = (const float2*)h2s;
    float2 self = h2[n];
    float a0 = self.x, a1 = self.y;
    int e = rp[n], e1 = rp[n + 1];
    for (; e + 4 <= e1; e += 4) {
        int p0 = packed2[e + 0] & 0xFFFFFF;
        int p1 = packed2[e + 1] & 0xFFFFFF;
        int p2 = packed2[e + 2] & 0xFFFFFF;
        int p3 = packed2[e + 3] & 0xFFFFFF;
        float2 v0 = h2[p0], v1 = h2[p1], v2 = h2[p2], v3 = h2[p3];
        a0 += v0.x + v1.x + v2.x + v3.x;
        a1 += v0.y + v1.y + v2.y + v3.y;
    }
    for (; e < e1; ++e) {
        int p = packed2[e] & 0xFFFFFF;
        float2 v = h2[p];
        a0 += v.x; a1 += v.y;
    }
    float dv = dinv[n];
    a0 = fmaf(a0, dv, b2[0]);
    a1 = fmaf(a1, dv, b2[1]);
    float m = fmaxf(a0, a1);
    float lse = m + logf(expf(a0 - m) + expf(a1 - m));
    ((float2*)out)[n] = make_float2(a0 - lse, a1 - lse);
}

extern "C" void kernel_launch(void* const* d_in, const int* in_sizes, int n_in,
                              void* d_out, int out_size, void* d_ws, size_t ws_size,
                              hipStream_t stream) {
    const float* x  = (const float*)d_in[0];
    const int* ei   = (const int*)d_in[1];
    const float* W1 = (const float*)d_in[2];
    const float* b1 = (const float*)d_in[3];
    const float* W2 = (const float*)d_in[4];
    const float* b2 = (const float*)d_in[5];
    float* out = (float*)d_out;

    const int N = in_sizes[0] / F_IN;     // 100000
    const int E = in_sizes[1] / 2;        // 3200000
    const int* src0 = ei;
    const int* dst0 = ei + E;

    const int K = (N + NPB - 1) >> LOG_NPB;      // 782
    const int nblk = (E + CH - 1) / CH;          // 782

    // workspace layout (float units), 16B-aligned chunks
    size_t off = 0;
    float* wsf = (float*)d_ws;
    auto take = [&](size_t nf) { float* p = wsf + off; off += (nf + 3) & ~(size_t)3; return p; };
    float* dinv    = take(N);
    __hip_bfloat16* h1b = (__hip_bfloat16*)take((size_t)N * H1 / 2);
    float* h2s     = take((size_t)N * C_OUT);
    int*   packed  = (int*)take(E);
    int*   packed2 = (int*)take(E);
    int*   cnt     = (int*)take((size_t)K * nblk);
    int*   tot     = (int*)take(K);
    int*   base_e  = (int*)take(K + 1);
    int*   rp      = (int*)take(N + 1);

    k_part_count<<<nblk, 256, 0, stream>>>(dst0, cnt, E, K, nblk);
    k_colscan<<<K, 1024, 0, stream>>>(cnt, tot, nblk);
    k_basescan<<<1, 1024, 0, stream>>>(tot, base_e, K);
    k_scatter<<<nblk, 256, 0, stream>>>(src0, dst0, cnt, base_e, packed, E, K, nblk);
    k_bucket<<<K, 256, 0, stream>>>(packed, base_e, packed2, rp, dinv, N, K, E);
    k_gemm1<<<(N + 15) / 16, 256, 0, stream>>>(x, W1, dinv, h1b, N);
    k_agg1<<<(2 * N + 255) / 256, 256, 0, stream>>>(packed2, rp, h1b, dinv, b1, W2, h2s, N);
    k_agg2<<<(N + 255) / 256, 256, 0, stream>>>(packed2, rp, h2s, dinv, b2, out, N);
}